// Round 4
// baseline (148.109 us; speedup 1.0000x reference)
//
#include <hip/hip_runtime.h>
#include <stdint.h>

#define TWF 0.2f
#define NPTS 16384

typedef __attribute__((ext_vector_type(8))) short short8;
typedef __attribute__((ext_vector_type(4))) float floatx4;

__device__ __forceinline__ short f2bf(float f){
  unsigned u = __float_as_uint(f);
  u += 0x7fff + ((u >> 16) & 1);           // round-to-nearest-even
  return (short)(u >> 16);
}
__device__ __forceinline__ float bf2f(short s){
  return __uint_as_float(((unsigned)(unsigned short)s) << 16);
}
// tanh(x) = 1 - 2/(exp2(2*log2e*x)+1); exact at +/-inf
__device__ __forceinline__ float fast_tanh(float x){
  float e = __builtin_amdgcn_exp2f(x * 2.885390082f);
  float r = __builtin_amdgcn_rcpf(e + 1.f);
  return fmaf(-2.f, r, 1.f);
}
// cos(pi*t) via v_cos (revolutions)
__device__ __forceinline__ float cospi_t(float t){
  return __builtin_amdgcn_cosf(t * 0.5f);
}
// packed f32x2 -> bf16x2 (RTNE in HW); low 16 = lo, high 16 = hi
__device__ __forceinline__ unsigned cvt_pk_bf16(float lo, float hi){
  unsigned r;
  asm("v_cvt_pk_bf16_f32 %0, %1, %2" : "=v"(r) : "v"(lo), "v"(hi));
  return r;
}

// ws layout (bytes):
//   [0, 4M)      : bf16-swizzled W1/W2
//   [4M, 8M)     : rec[16][16384] float4 {xn0, xn1, win, pidx-bits}
//   [8M, 8M+4K)  : counts[16], 128B stride (one L2 line each)
#define WS_W      0
#define WS_REC    (4u<<20)
#define WS_CNT    (8u<<20)
#define CNT(k)    counts[(k) * 32]

// Fused: blocks [0,1024) convert W1/W2 to bf16 fragment order;
// blocks [1024,1280) zero `out` and build per-k compacted point RECORDS
// {xn0,xn1,win,pidx}. Each block handles ONE k for 1024 points (4/thread):
// exactly ONE atomic per block -> 16 contenders per k-line (was 64), and no
// serial per-block rounds (ballot aggregation is intra-wave, barrier-free).
__global__ __launch_bounds__(256) void prep_fused(
    const float* __restrict__ W1, const float* __restrict__ W2,
    const float* __restrict__ x,  const float* __restrict__ xmins,
    const float* __restrict__ xmaxs, short* __restrict__ dst,
    int* __restrict__ counts, floatx4* __restrict__ rec,
    float* __restrict__ out){
  if (blockIdx.x < 1024){
    int gid = blockIdx.x * 256 + threadIdx.x;   // 2*16*8*16*64 = 262144 total
    int lane = gid & 63; int rest = gid >> 6;
    int jt = rest & 15; rest >>= 4;
    int ks = rest & 7;  rest >>= 3;
    int k  = rest & 15; int mat = rest >> 4;
    const float* W = mat ? W2 : W1;
    int j   = jt * 16 + (lane & 15);
    int kk0 = ks * 32 + (lane >> 4) * 8;
    short8 v;
    #pragma unroll
    for (int jj = 0; jj < 8; jj++)
      v[jj] = f2bf(W[k * 65536 + (kk0 + jj) * 256 + j]);
    *(short8*)(dst + (size_t)gid * 8) = v;
  } else {
    __shared__ int s_wrt[4][4];                  // [wave][round] actives
    __shared__ int s_base;
    int b2   = blockIdx.x - 1024;                // [0,256)
    int k    = b2 & 15;                          // this block's subdomain
    int cb   = (b2 >> 4) * 1024;                 // chunk base point
    int t    = threadIdx.x;
    int lane = t & 63, wave = t >> 6;

    float cx  = (xmins[k * 2 + 0] + xmaxs[k * 2 + 0]) * 0.5f;
    float cy  = (xmins[k * 2 + 1] + xmaxs[k * 2 + 1]) * 0.5f;
    float sxi = 1.f / fmaxf((xmaxs[k * 2 + 0] - xmins[k * 2 + 0]) * 0.5f, 1e-9f);
    float syi = 1.f / fmaxf((xmaxs[k * 2 + 1] - xmins[k * 2 + 1]) * 0.5f, 1e-9f);

    float pxr[4], pyr[4], sum[4], wk[4];
    #pragma unroll
    for (int r = 0; r < 4; r++){
      int p = cb + r * 256 + t;
      float2 xy = *(const float2*)&x[p * 2];
      pxr[r] = xy.x; pyr[r] = xy.y; sum[r] = 0.f; wk[r] = 0.f;
      if (k == 0) out[p] = 0.f;                  // fold memset(out), once
    }
    #pragma unroll
    for (int kk = 0; kk < 16; kk++){
      float mnx = xmins[kk * 2 + 0], mny = xmins[kk * 2 + 1];
      float mxx = xmaxs[kk * 2 + 0], mxy = xmaxs[kk * 2 + 1];
      #pragma unroll
      for (int r = 0; r < 4; r++){
        float tlx = fminf(fmaxf((pxr[r] - (mnx - TWF)) * (1.f/(2.f*TWF)), 0.f), 1.f);
        float trx = fminf(fmaxf(((mxx + TWF) - pxr[r]) * (1.f/(2.f*TWF)), 0.f), 1.f);
        float tly = fminf(fmaxf((pyr[r] - (mny - TWF)) * (1.f/(2.f*TWF)), 0.f), 1.f);
        float tr2 = fminf(fmaxf(((mxy + TWF) - pyr[r]) * (1.f/(2.f*TWF)), 0.f), 1.f);
        float wx = 0.25f * (1.f - cospi_t(tlx)) * (1.f - cospi_t(trx));
        float wy = 0.25f * (1.f - cospi_t(tly)) * (1.f - cospi_t(tr2));
        float w  = wx * wy;
        sum[r] += w;
        if (kk == k) wk[r] = w;
      }
    }
    bool act[4]; float wn[4], xa[4], xb[4];
    unsigned long long msk[4]; int wtot[4];
    #pragma unroll
    for (int r = 0; r < 4; r++){
      float inv = 1.f / (sum[r] + 1e-9f);
      act[r] = wk[r] > 0.f;
      wn[r]  = wk[r] * inv;
      xa[r]  = (pxr[r] - cx) * sxi;
      xb[r]  = (pyr[r] - cy) * syi;
      msk[r] = __ballot(act[r]);
      wtot[r] = (int)__popcll(msk[r]);
    }
    if (lane == 0){
      #pragma unroll
      for (int r = 0; r < 4; r++) s_wrt[wave][r] = wtot[r];
    }
    __syncthreads();
    int wavebase = 0, blocktot = 0;
    #pragma unroll
    for (int w = 0; w < 4; w++){
      int ws_ = s_wrt[w][0] + s_wrt[w][1] + s_wrt[w][2] + s_wrt[w][3];
      blocktot += ws_;
      wavebase += (w < wave) ? ws_ : 0;
    }
    if (t == 0) s_base = atomicAdd(&CNT(k), blocktot);
    __syncthreads();
    int rb = 0;
    #pragma unroll
    for (int r = 0; r < 4; r++){
      if (act[r]){
        int pos = s_base + wavebase + rb +
                  (int)__popcll(msk[r] & ((1ull << lane) - 1ull));
        int p = cb + r * 256 + t;
        rec[k * NPTS + pos] = (floatx4){xa[r], xb[r], wn[r], __int_as_float(p)};
      }
      rb += s_wrt[wave][r];
    }
  }
}

// Packed tanh+bf16 writeback: acc[rt][ct] holds D[j'][m] with
// j' = (wave*4+rt)*16 + quad*4 + r (4 CONSECUTIVE rows) and m = ct*16+col.
// One cvt_pk pair + one 8B ds_write per 4 elements, into the chunk-XOR
// swizzled [m][j] layout (same layout the B-frag reads & layer3 expect).
__device__ __forceinline__ void store_h_packed(
    short* lds_h, const floatx4 (&acc)[4][4], const floatx4 (&bb)[4],
    int wave, int quad, int col){
  #pragma unroll
  for (int rt = 0; rt < 4; rt++){
    const int j0    = (wave * 4 + rt) * 16 + quad * 4;
    const int cbase = j0 >> 3;
    const int off   = j0 & 7;                 // 0 or 4 within the 8-short chunk
    #pragma unroll
    for (int ct = 0; ct < 4; ct++){
      const int m = ct * 16 + col;
      float t0 = fast_tanh(acc[rt][ct][0] + bb[rt][0]);
      float t1 = fast_tanh(acc[rt][ct][1] + bb[rt][1]);
      float t2 = fast_tanh(acc[rt][ct][2] + bb[rt][2]);
      float t3 = fast_tanh(acc[rt][ct][3] + bb[rt][3]);
      uint2 v = make_uint2(cvt_pk_bf16(t0, t1), cvt_pk_bf16(t2, t3));
      *(uint2*)&lds_h[m * 256 + ((cbase ^ (m & 7)) << 3) + off] = v;
    }
  }
}

__global__ __launch_bounds__(256, 4) void fbpinn_main(
    const float* __restrict__ W0, const float* __restrict__ b0,
    const float* __restrict__ b1, const float* __restrict__ b2,
    const float* __restrict__ W3, const float* __restrict__ b3,
    const short* __restrict__ wsw, const int* __restrict__ counts,
    const floatx4* __restrict__ rec, float* __restrict__ out)
{
  __shared__ short lds_h[64 * 256];   // 32 KB, swizzled bf16 h tile, [m][j]
  __shared__ float s_xn[64 * 2];
  __shared__ float s_win[64];
  __shared__ int   s_pidx[64];
  __shared__ float s_w3[256];
  __shared__ float s_w0[512];

  const int t    = threadIdx.x;
  const int lane = t & 63;
  const int wave = t >> 6;
  const int col  = lane & 15;
  const int quad = lane >> 4;

  // live-tile partition: prefix over per-k tile counts
  int tb[17]; tb[0] = 0;
  #pragma unroll
  for (int kk = 0; kk < 16; kk++) tb[kk + 1] = tb[kk] + ((CNT(kk) + 63) >> 6);
  const int total = tb[16];

  // XCD-chunked tile mapping: tiles are k-major; each XCD gets a CONTIGUOUS
  // chunk so its private L2 sees ~2 weight panels. Grid 1024 = 4 blocks/CU
  // exactly (LDS cap), ONE scheduling generation; ~1/3 of blocks run a 2nd
  // tile which overlaps with residents instead of waiting for an LDS slot.
  const int xcd   = blockIdx.x & 7;
  const int nb    = gridDim.x >> 3;        // blocks per xcd
  const int chunk = (total + 7) >> 3;      // tiles per xcd

  for (int idx = blockIdx.x >> 3; idx < chunk; idx += nb){
    const int tile = xcd * chunk + idx;
    if (tile >= total) break;
    int k = 0;
    #pragma unroll
    for (int kk = 1; kk < 16; kk++) k += (tile >= tb[kk]);
    const int base = (tile - tb[k]) * 64;
    const int cnt  = CNT(k);

    __syncthreads();   // previous tile's layer-3 reads done before s_* overwrite

    // ---- stage: ONE coalesced 16B record per point (no dependent gather) ----
    s_w3[t] = W3[k * 256 + t];
    s_w0[t] = W0[k * 512 + t];
    s_w0[256 + t] = W0[k * 512 + 256 + t];
    if (t < 64){
      int gi = base + t;
      bool valid = gi < cnt;
      floatx4 rc = rec[k * NPTS + (valid ? gi : 0)];
      s_pidx[t] = __float_as_int(rc[3]);
      s_win[t]  = valid ? rc[2] : 0.f;
      s_xn[t * 2 + 0] = rc[0];
      s_xn[t * 2 + 1] = rc[1];
    }
    __syncthreads();

    // ---- layer 0 (D=2 -> 256), swapped roles: D[j'][m] = W0^T(j',d) * xn^T(d,m) ----
    {
      short8 wfr[4], xfr[4];
      #pragma unroll
      for (int rt = 0; rt < 4; rt++){
        int j = (wave * 4 + rt) * 16 + col;        // A row = out-feature j'
        short8 a;
        #pragma unroll
        for (int i = 0; i < 8; i++) a[i] = 0;
        a[0] = (quad == 0) ? f2bf(s_w0[j])       : (short)0;
        a[1] = (quad == 0) ? f2bf(s_w0[256 + j]) : (short)0;
        wfr[rt] = a;
      }
      #pragma unroll
      for (int ct = 0; ct < 4; ct++){
        int m = ct * 16 + col;                     // B col = point m
        short8 b;
        #pragma unroll
        for (int i = 0; i < 8; i++) b[i] = 0;
        b[0] = (quad == 0) ? f2bf(s_xn[m * 2 + 0]) : (short)0;
        b[1] = (quad == 0) ? f2bf(s_xn[m * 2 + 1]) : (short)0;
        xfr[ct] = b;
      }
      floatx4 bb[4];
      #pragma unroll
      for (int rt = 0; rt < 4; rt++)
        bb[rt] = *(const floatx4*)&b0[k * 256 + (wave * 4 + rt) * 16 + quad * 4];
      floatx4 acc[4][4];
      #pragma unroll
      for (int a = 0; a < 4; a++)
        #pragma unroll
        for (int b = 0; b < 4; b++)
          acc[a][b] = (floatx4){0.f, 0.f, 0.f, 0.f};
      #pragma unroll
      for (int rt = 0; rt < 4; rt++)
        #pragma unroll
        for (int ct = 0; ct < 4; ct++)
          acc[rt][ct] = __builtin_amdgcn_mfma_f32_16x16x32_bf16(wfr[rt], xfr[ct], acc[rt][ct], 0, 0, 0);
      store_h_packed(lds_h, acc, bb, wave, quad, col);
      __syncthreads();
    }

    // ---- layers 1,2: D[j'][m] = W^T * h^T; weights = A (global), h = B (LDS) ----
    #pragma unroll 1
    for (int layer = 0; layer < 2; layer++){
      const short8* wb = (const short8*)(wsw + (size_t)layer * 1048576)
                         + ((size_t)(k * 8) * 16 + wave * 4) * 64 + lane;
      const float*  bp = layer ? b2 : b1;
      floatx4 bb[4];
      #pragma unroll
      for (int rt = 0; rt < 4; rt++)
        bb[rt] = *(const floatx4*)&bp[k * 256 + (wave * 4 + rt) * 16 + quad * 4];
      floatx4 acc[4][4];
      #pragma unroll
      for (int a = 0; a < 4; a++)
        #pragma unroll
        for (int b = 0; b < 4; b++)
          acc[a][b] = (floatx4){0.f, 0.f, 0.f, 0.f};

      short8 wcur[4];
      #pragma unroll
      for (int rt = 0; rt < 4; rt++) wcur[rt] = wb[rt * 64];

      #pragma unroll
      for (int ks = 0; ks < 8; ks++){
        short8 wnxt[4];
        if (ks < 7){
          #pragma unroll
          for (int rt = 0; rt < 4; rt++)
            wnxt[rt] = wb[(ks + 1) * 1024 + rt * 64];   // prefetch next K-step
        }
        short8 hfr[4];
        #pragma unroll
        for (int ct = 0; ct < 4; ct++){
          int m   = ct * 16 + col;                 // B: col = point m
          int pos = (ks * 4 + quad) ^ (m & 7);     // B: k-chunk = quad
          hfr[ct] = *(const short8*)&lds_h[m * 256 + pos * 8];
        }
        #pragma unroll
        for (int rt = 0; rt < 4; rt++)
          #pragma unroll
          for (int ct = 0; ct < 4; ct++)
            acc[rt][ct] = __builtin_amdgcn_mfma_f32_16x16x32_bf16(wcur[rt], hfr[ct], acc[rt][ct], 0, 0, 0);
        if (ks < 7){
          #pragma unroll
          for (int rt = 0; rt < 4; rt++) wcur[rt] = wnxt[rt];
        }
      }
      __syncthreads();   // all reads of h done before overwrite

      store_h_packed(lds_h, acc, bb, wave, quad, col);
      __syncthreads();
    }

    // ---- layer 3 (256 -> 1) + window-weighted scatter ----
    {
      int m = t >> 2, q = t & 3;     // 4 threads per point
      float dot = 0.f;
      #pragma unroll
      for (int cc = 0; cc < 8; cc++){
        int ci  = q * 8 + cc;
        int pos = ci ^ (m & 7);
        short8 hv = *(const short8*)&lds_h[m * 256 + pos * 8];
        #pragma unroll
        for (int jj = 0; jj < 8; jj++)
          dot = fmaf(bf2f(hv[jj]), s_w3[ci * 8 + jj], dot);
      }
      dot += __shfl_xor(dot, 1);
      dot += __shfl_xor(dot, 2);
      if (q == 0 && s_win[m] != 0.f)
        atomicAdd(&out[s_pidx[m]], s_win[m] * (dot + b3[k]));
    }
  }
}

extern "C" void kernel_launch(void* const* d_in, const int* in_sizes, int n_in,
                              void* d_out, int out_size, void* d_ws, size_t ws_size,
                              hipStream_t stream){
  const float* x     = (const float*)d_in[0];
  const float* W0    = (const float*)d_in[1];
  const float* b0    = (const float*)d_in[2];
  const float* W1    = (const float*)d_in[3];
  const float* b1    = (const float*)d_in[4];
  const float* W2    = (const float*)d_in[5];
  const float* b2    = (const float*)d_in[6];
  const float* W3    = (const float*)d_in[7];
  const float* b3    = (const float*)d_in[8];
  const float* xmins = (const float*)d_in[9];
  const float* xmaxs = (const float*)d_in[10];
  float* out = (float*)d_out;

  char* ws = (char*)d_ws;                     // needs ~8.01 MB
  short*   wsw  = (short*)  (ws + WS_W);
  floatx4* rc   = (floatx4*)(ws + WS_REC);
  int*     cnts = (int*)    (ws + WS_CNT);

  (void)hipMemsetAsync(cnts, 0, 4096, stream);
  prep_fused<<<1024 + 256, 256, 0, stream>>>(W1, W2, x, xmins, xmaxs,
                                             wsw, cnts, rc, out);
  fbpinn_main<<<1024, 256, 0, stream>>>(W0, b0, b1, b2, W3, b3,
                                        wsw, cnts, rc, out);
}